// Round 4
// baseline (162.640 us; speedup 1.0000x reference)
//
#include <hip/hip_runtime.h>
#include <math.h>

#define NTOK 32768
#define KCB  1024
#define DIM  64

// ---- workspace layout (float offsets) ----
#define WS_XR      0                       // [NTOK*64] rotated vectors
#define WS_ENORM   2097152                 // [1024] ||e_k||^2
#define WS_COUNTS  (WS_ENORM + 1024)       // [1024] float counts
#define WS_CS      (WS_COUNTS + 1024)      // [1024] smoothed cluster size
#define WS_XRSUM   (WS_CS + 1024)          // [64]   sum_n xr[n][d]
#define WS_ESUM    (WS_XRSUM + 64)         // [64]   sum_k c_k*emb[k][d]
#define WS_SCAL    (WS_ESUM + 64)          // [16]: 0=sq_sum 1=xrnorm_sum 2=c*||emb||^2
#define WS_PMIN    (WS_SCAL + 16)          // [2*NTOK] partial min per k-half
#define WS_PIDX    (WS_PMIN + 65536)       // [2*NTOK] (int)
#define WS_IDX     (WS_PIDX + 65536)       // [NTOK]   (int)
// dead-region aliases (after merge, pmin/pidx are free):
#define WS_SORT    WS_PMIN                 // [NTOK] (int) code-sorted token ids
#define WS_OFF     WS_PIDX                 // [1024] (int) segment offsets
#define WS_CUR     (WS_PIDX + 1024)        // [1024] (int) scatter cursors

// ---- output layout (float offsets) ----
#define O_Q    0
#define O_CB   2097152
#define O_CM   2097153
#define O_DV   2097154
#define O_PP   2097155
#define O_IDX  2097156
#define O_CS   2129924
#define O_EW   2130948
#define O_EMB  2196484

// ---------------------------------------------------------------------------
// 1) rotate via cross-lane FWHT; blocks >= 512 compute codebook norms.
__global__ __launch_bounds__(256) void k_rotate_enorm(const float* __restrict__ x,
    const float* __restrict__ E, float* __restrict__ xr, float* __restrict__ enorm,
    float* __restrict__ xr_sum, float* __restrict__ scal)
{
    int tid = threadIdx.x;
    if (blockIdx.x >= 512) {   // enorm blocks
        int k = ((int)blockIdx.x - 512) * 256 + tid;
        const float4* e4 = (const float4*)(E + ((size_t)k << 6));
        float s = 0.f;
        #pragma unroll
        for (int q = 0; q < 16; ++q) {
            float4 v = e4[q];
            s += v.x*v.x + v.y*v.y + v.z*v.z + v.w*v.w;
        }
        enorm[k] = s;
        return;
    }
    __shared__ float xs[4][64];
    __shared__ float wred[4];
    int lane = tid & 63, w = tid >> 6;
    int g = blockIdx.x * 4 + w;            // wave id 0..2047
    float dsum = 0.f, nrm = 0.f;
    #pragma unroll
    for (int i = 0; i < 4; ++i) {
        int t0 = g * 16 + i * 4;
        const float* src = x + ((size_t)(t0 >> 10) << 16) + lane * 1024 + (t0 & 1023);
        float4 v = *(const float4*)src;
        #pragma unroll
        for (int s = 1; s <= 32; s <<= 1) {
            float sgn = (lane & s) ? -1.f : 1.f;
            float ox = __shfl_xor(v.x, s);
            float oy = __shfl_xor(v.y, s);
            float oz = __shfl_xor(v.z, s);
            float ow = __shfl_xor(v.w, s);
            v.x = fmaf(sgn, v.x, ox);
            v.y = fmaf(sgn, v.y, oy);
            v.z = fmaf(sgn, v.z, oz);
            v.w = fmaf(sgn, v.w, ow);
        }
        float* dst = xr + ((size_t)t0 << 6) + lane;
        dst[0]   = v.x;
        dst[64]  = v.y;
        dst[128] = v.z;
        dst[192] = v.w;
        dsum += v.x + v.y + v.z + v.w;
        nrm  += v.x*v.x + v.y*v.y + v.z*v.z + v.w*v.w;
    }
    xs[w][lane] = dsum;
    #pragma unroll
    for (int m = 32; m >= 1; m >>= 1) nrm += __shfl_xor(nrm, m);
    if (lane == 0) wred[w] = nrm;
    __syncthreads();
    if (tid < 64) atomicAdd(&xr_sum[tid], xs[0][tid] + xs[1][tid] + xs[2][tid] + xs[3][tid]);
    if (tid == 0) atomicAdd(&scal[1], wred[0] + wred[1] + wred[2] + wred[3]);
}

// ---------------------------------------------------------------------------
// 2) fused distance GEMM + argmin, inner-product form, NO transpose.
//    Block = 128 tokens x 512 codes (k-split 2). LDS row-major [row][68].
//    Thread (tx,ty) owns tokens {16i+ty} x codes {16j+tx}; per-d4 reads are
//    conflict-free (a: 4 uniq addrs banks 4ty+dw; b: 2-way banks 4tx+dw).
//    E chunks prefetched to registers (T14), written to LDS after barrier.
#define XLD 68
__global__ __launch_bounds__(256, 2) void k_argmin(const float* __restrict__ xr,
    const float* __restrict__ E, const float* __restrict__ enorm,
    float* __restrict__ pmin, int* __restrict__ pidx)
{
    __shared__ float xs[128 * XLD];
    __shared__ float es[128 * XLD];
    int tid = threadIdx.x;
    int tx = tid & 15, ty = tid >> 4;
    int nb = blockIdx.x >> 1, kh = blockIdx.x & 1;
    int n0 = nb << 7;

    // stage xr tile row-major (straight copy, contiguous writes)
    {
        const float4* src = (const float4*)(xr + ((size_t)n0 << 6));
        #pragma unroll
        for (int it = 0; it < 8; ++it) {
            int q = (it << 8) + tid;
            int row = q >> 4, c4 = (q & 15) << 2;
            *(float4*)(xs + row * XLD + c4) = src[q];
        }
    }
    // prologue: prefetch E chunk 0 into registers
    float4 pf[8];
    {
        const float4* esrc = (const float4*)(E + ((size_t)(kh << 9) << 6));
        #pragma unroll
        for (int it = 0; it < 8; ++it) pf[it] = esrc[(it << 8) + tid];
    }

    float best[8]; int bidx[8];
    #pragma unroll
    for (int i = 0; i < 8; ++i) { best[i] = 3.4e38f; bidx[i] = 0; }

    for (int kc = 0; kc < 4; ++kc) {
        int kbase = (kh << 9) + (kc << 7);
        __syncthreads();                    // prev chunk reads done; xs staged
        #pragma unroll
        for (int it = 0; it < 8; ++it) {
            int q = (it << 8) + tid;
            int row = q >> 4, c4 = (q & 15) << 2;
            *(float4*)(es + row * XLD + c4) = pf[it];
        }
        if (kc < 3) {                       // prefetch next chunk (hides under compute)
            const float4* esrc = (const float4*)(E + ((size_t)(kbase + 128) << 6));
            #pragma unroll
            for (int it = 0; it < 8; ++it) pf[it] = esrc[(it << 8) + tid];
        }
        __syncthreads();

        float acc[8][8];
        #pragma unroll
        for (int i = 0; i < 8; ++i)
            #pragma unroll
            for (int j = 0; j < 8; ++j) acc[i][j] = 0.f;

        #pragma unroll 2
        for (int d4 = 0; d4 < 16; ++d4) {
            int dw = d4 << 2;
            float4 a8[8];
            #pragma unroll
            for (int i = 0; i < 8; ++i)
                a8[i] = *(const float4*)(xs + (16 * i + ty) * XLD + dw);
            #pragma unroll
            for (int j = 0; j < 8; ++j) {
                float4 b = *(const float4*)(es + (16 * j + tx) * XLD + dw);
                #pragma unroll
                for (int i = 0; i < 8; ++i) {
                    float t = fmaf(a8[i].x, b.x, acc[i][j]);
                    t = fmaf(a8[i].y, b.y, t);
                    t = fmaf(a8[i].z, b.z, t);
                    acc[i][j] = fmaf(a8[i].w, b.w, t);
                }
            }
        }

        // fold: s = ||e||^2 - 2*dot ; codes ascending in j for tie-break
        #pragma unroll
        for (int j = 0; j < 8; ++j) {
            int k = kbase + 16 * j + tx;
            float en = enorm[k];
            #pragma unroll
            for (int i = 0; i < 8; ++i) {
                float s = fmaf(-2.f, acc[i][j], en);
                if (s < best[i]) { best[i] = s; bidx[i] = k; }
            }
        }
    }

    // reduce across the 16 tx lanes (bits 0-3 of lane id)
    #pragma unroll
    for (int i = 0; i < 8; ++i) {
        float v = best[i]; int id = bidx[i];
        #pragma unroll
        for (int m = 8; m >= 1; m >>= 1) {
            float v2 = __shfl_xor(v, m);
            int id2 = __shfl_xor(id, m);
            if (v2 < v || (v2 == v && id2 < id)) { v = v2; id = id2; }
        }
        if (tx == 0) {
            int r = n0 + 16 * i + ty;
            pmin[(kh << 15) + r] = v;
            pidx[(kh << 15) + r] = id;
        }
    }
}

// ---------------------------------------------------------------------------
// 3) merge k-halves + counts + fused quant output & sq-error
__global__ __launch_bounds__(256) void k_mergequant(const float* __restrict__ pmin,
    const int* __restrict__ pidx, const float* __restrict__ x,
    const float* __restrict__ E, int* __restrict__ idxw,
    float* __restrict__ out_idx, float* __restrict__ counts,
    float* __restrict__ outq, float* __restrict__ scal)
{
    __shared__ int lidx[256];
    __shared__ float wr[4];
    int tid = threadIdx.x;
    int n = blockIdx.x * 256 + tid;
    float v0 = pmin[n];          int i0 = pidx[n];
    float v1 = pmin[32768 + n];  int i1 = pidx[32768 + n];
    int k = (v1 < v0 || (v1 == v0 && i1 < i0)) ? i1 : i0;
    idxw[n] = k;
    out_idx[n] = (float)k;
    atomicAdd(&counts[k], 1.0f);
    lidx[tid] = k;
    __syncthreads();

    int f40 = blockIdx.x * 4096;
    float sq = 0.f;
    #pragma unroll 4
    for (int it = 0; it < 16; ++it) {
        int q = (it << 8) + tid;
        int kk = lidx[q >> 4];
        int d4 = q & 15;
        float4 xv = ((const float4*)x)[f40 + q];
        float4 ev = ((const float4*)E)[(kk << 4) + d4];
        float dx = ev.x - xv.x, dy = ev.y - xv.y, dz = ev.z - xv.z, dw_ = ev.w - xv.w;
        ((float4*)outq)[f40 + q] = make_float4(xv.x + dx, xv.y + dy, xv.z + dz, xv.w + dw_);
        sq += dx*dx + dy*dy + dz*dz + dw_*dw_;
    }
    #pragma unroll
    for (int m = 32; m >= 1; m >>= 1) sq += __shfl_xor(sq, m);
    if ((tid & 63) == 0) wr[tid >> 6] = sq;
    __syncthreads();
    if (tid == 0) atomicAdd(&scal[0], wr[0] + wr[1] + wr[2] + wr[3]);
}

// ---------------------------------------------------------------------------
// 4) EMA cluster size + smoothing + exclusive scan (wave-shuffle version)
__global__ __launch_bounds__(1024) void k_ema_scan(const float* __restrict__ ecs,
    const float* __restrict__ counts, float* __restrict__ out_cs,
    float* __restrict__ csw, int* __restrict__ off, int* __restrict__ cur)
{
    __shared__ float wsum[16];
    __shared__ int   wcnt[16];
    __shared__ int   woff[16];
    __shared__ float nss;
    int k = threadIdx.x;
    int lane = k & 63, w = k >> 6;
    float c = counts[k];
    float cs = ecs[k] * 0.99f + 0.01f * c;
    int ci = (int)c;
    // wave inclusive scan of ci
    int sc = ci;
    #pragma unroll
    for (int o = 1; o < 64; o <<= 1) {
        int t = __shfl_up(sc, o);
        if (lane >= o) sc += t;
    }
    // wave sum of cs
    float v = cs;
    #pragma unroll
    for (int m = 32; m >= 1; m >>= 1) v += __shfl_xor(v, m);
    if (lane == 63) wcnt[w] = sc;
    if (lane == 0)  wsum[w] = v;
    __syncthreads();
    if (k < 16) {
        int t = wcnt[k];
        int e = t;
        #pragma unroll
        for (int o = 1; o < 16; o <<= 1) {
            int u = __shfl_up(e, o);
            if (k >= o) e += u;
        }
        woff[k] = e - t;
        if (k == 15) {
            float s = 0.f;
            for (int i = 0; i < 16; ++i) s += wsum[i];
            nss = s;
        }
    }
    __syncthreads();
    int offk = woff[w] + sc - ci;
    off[k] = offk;
    cur[k] = offk;
    float nn = nss;
    float csf = (cs + 1e-5f) / (nn + 1024.f * 1e-5f) * nn;
    out_cs[k] = csf;
    csw[k] = csf;
}

// ---------------------------------------------------------------------------
// 5) counting-sort scatter
__global__ __launch_bounds__(256) void k_scatter(const int* __restrict__ idxw,
    int* __restrict__ cur, int* __restrict__ sorted)
{
    int n = blockIdx.x * 256 + threadIdx.x;
    int k = idxw[n];
    int pos = atomicAdd(&cur[k], 1);
    sorted[pos] = n;
}

// ---------------------------------------------------------------------------
// 6) per-code segmented reduction -> new_ema_w, new_embedding, diversity
__global__ __launch_bounds__(256) void k_dwemb(const float* __restrict__ xr,
    const int* __restrict__ sorted, const int* __restrict__ off,
    const float* __restrict__ counts, const float* __restrict__ csw,
    const float* __restrict__ emaw, float* __restrict__ out_ew,
    float* __restrict__ out_emb, float* __restrict__ e_sum,
    float* __restrict__ scal)
{
    __shared__ float part[3][64];
    int k = blockIdx.x;
    int tid = threadIdx.x;
    int w = tid >> 6, d = tid & 63;
    int a = off[k];
    int cnt = (int)counts[k];
    int end = a + cnt;

    float sum = 0.f;
    for (int t = a + w; t < end; t += 4) {
        int tok = sorted[t];
        sum += xr[((size_t)tok << 6) + d];
    }
    if (w) part[w - 1][d] = sum;
    __syncthreads();
    if (w == 0) {
        float dw = sum + part[0][d] + part[1][d] + part[2][d];
        int i = (k << 6) + d;
        float nw = emaw[i] * 0.99f + 0.01f * dw;
        out_ew[i] = nw;
        float emb = nw / csw[k];
        out_emb[i] = emb;
        if (cnt > 0) {
            float c = (float)cnt;
            atomicAdd(&e_sum[d], c * emb);
            float t2 = c * emb * emb;
            #pragma unroll
            for (int m = 32; m >= 1; m >>= 1) t2 += __shfl_xor(t2, m);
            if (d == 0) atomicAdd(&scal[2], t2);
        }
    }
}

// ---------------------------------------------------------------------------
// 7) finalize scalars
__global__ __launch_bounds__(1024) void k_final(const float* __restrict__ counts,
    const float* __restrict__ scal, const float* __restrict__ xr_sum,
    const float* __restrict__ e_sum, float* __restrict__ out)
{
    int tid = threadIdx.x;
    float a = counts[tid] * (1.f / 32768.f);
    float t = a * logf(a + 1e-10f);
    float dc = (tid < 64) ? e_sum[tid] * xr_sum[tid] : 0.f;
    #pragma unroll
    for (int m = 32; m >= 1; m >>= 1) { t += __shfl_xor(t, m); dc += __shfl_xor(dc, m); }
    __shared__ float wt[16], wd[16];
    if ((tid & 63) == 0) { wt[tid >> 6] = t; wd[tid >> 6] = dc; }
    __syncthreads();
    if (tid == 0) {
        float S = 0.f, Dt = 0.f;
        for (int i = 0; i < 16; ++i) { S += wt[i]; Dt += wd[i]; }
        float cb = scal[0] * (1.f / 2097152.f);
        out[O_CB] = cb;
        out[O_CM] = 0.25f * cb;
        float inv = 1.f / 32768.f;
        out[O_DV] = scal[2] * inv + scal[1] * inv - 2.f * (Dt * inv * inv);
        out[O_PP] = expf(-S);
    }
}

// ---------------------------------------------------------------------------
extern "C" void kernel_launch(void* const* d_in, const int* in_sizes, int n_in,
                              void* d_out, int out_size, void* d_ws, size_t ws_size,
                              hipStream_t stream)
{
    const float* x    = (const float*)d_in[0];
    const float* E    = (const float*)d_in[1];
    const float* emaw = (const float*)d_in[3];
    const float* ecs  = (const float*)d_in[4];
    float* out = (float*)d_out;
    float* ws  = (float*)d_ws;

    hipMemsetAsync((void*)(ws + WS_COUNTS), 0,
                   (size_t)(WS_PMIN - WS_COUNTS) * sizeof(float), stream);

    hipLaunchKernelGGL(k_rotate_enorm, dim3(516), dim3(256), 0, stream,
                       x, E, ws + WS_XR, ws + WS_ENORM, ws + WS_XRSUM, ws + WS_SCAL);
    hipLaunchKernelGGL(k_argmin, dim3(512), dim3(256), 0, stream,
                       ws + WS_XR, E, ws + WS_ENORM,
                       ws + WS_PMIN, (int*)(ws + WS_PIDX));
    hipLaunchKernelGGL(k_mergequant, dim3(128), dim3(256), 0, stream,
                       ws + WS_PMIN, (const int*)(ws + WS_PIDX), x, E,
                       (int*)(ws + WS_IDX), out + O_IDX, ws + WS_COUNTS,
                       out + O_Q, ws + WS_SCAL);
    hipLaunchKernelGGL(k_ema_scan, dim3(1), dim3(1024), 0, stream,
                       ecs, ws + WS_COUNTS, out + O_CS, ws + WS_CS,
                       (int*)(ws + WS_OFF), (int*)(ws + WS_CUR));
    hipLaunchKernelGGL(k_scatter, dim3(128), dim3(256), 0, stream,
                       (const int*)(ws + WS_IDX), (int*)(ws + WS_CUR),
                       (int*)(ws + WS_SORT));
    hipLaunchKernelGGL(k_dwemb, dim3(1024), dim3(256), 0, stream,
                       ws + WS_XR, (const int*)(ws + WS_SORT),
                       (const int*)(ws + WS_OFF), ws + WS_COUNTS, ws + WS_CS,
                       emaw, out + O_EW, out + O_EMB, ws + WS_ESUM, ws + WS_SCAL);
    hipLaunchKernelGGL(k_final, dim3(1), dim3(1024), 0, stream,
                       ws + WS_COUNTS, ws + WS_SCAL, ws + WS_XRSUM,
                       ws + WS_ESUM, out);
}

// Round 5
// 151.908 us; speedup vs baseline: 1.0707x; 1.0707x over previous
//
#include <hip/hip_runtime.h>
#include <math.h>

#define NTOK 32768
#define KCB  1024
#define DIM  64

// ---- workspace layout (float offsets) ----
#define WS_XR      0                       // [NTOK*64] rotated vectors
#define WS_ENORM   2097152                 // [1024] ||e_k||^2
#define WS_COUNTS  (WS_ENORM + 1024)       // [1024] float counts
#define WS_CS      (WS_COUNTS + 1024)      // [1024] smoothed cluster size
#define WS_XRSUM   (WS_CS + 1024)          // [64]   sum_n xr[n][d]
#define WS_ESUM    (WS_XRSUM + 64)         // [64]   sum_k c_k*emb[k][d]
#define WS_SCAL    (WS_ESUM + 64)          // [16]: 0=sq_sum 1=xrnorm_sum 2=c*||emb||^2
#define WS_PMIN    (WS_SCAL + 16)          // [2*NTOK] partial min per k-half
#define WS_PIDX    (WS_PMIN + 65536)       // [2*NTOK] (int)
#define WS_IDX     (WS_PIDX + 65536)       // [NTOK]   (int)
// dead-region aliases (after merge, pmin/pidx are free):
#define WS_SORT    WS_PMIN                 // [NTOK] (int) code-sorted token ids
#define WS_OFF     WS_PIDX                 // [1024] (int) segment offsets
#define WS_CUR     (WS_PIDX + 1024)        // [1024] (int) scatter cursors

// ---- output layout (float offsets) ----
#define O_Q    0
#define O_CB   2097152
#define O_CM   2097153
#define O_DV   2097154
#define O_PP   2097155
#define O_IDX  2097156
#define O_CS   2129924
#define O_EW   2130948
#define O_EMB  2196484

// ---------------------------------------------------------------------------
// 1) rotate via cross-lane FWHT; blocks >= 512 compute codebook norms.
__global__ __launch_bounds__(256) void k_rotate_enorm(const float* __restrict__ x,
    const float* __restrict__ E, float* __restrict__ xr, float* __restrict__ enorm,
    float* __restrict__ xr_sum, float* __restrict__ scal)
{
    int tid = threadIdx.x;
    if (blockIdx.x >= 512) {   // enorm blocks
        int k = ((int)blockIdx.x - 512) * 256 + tid;
        const float4* e4 = (const float4*)(E + ((size_t)k << 6));
        float s = 0.f;
        #pragma unroll
        for (int q = 0; q < 16; ++q) {
            float4 v = e4[q];
            s += v.x*v.x + v.y*v.y + v.z*v.z + v.w*v.w;
        }
        enorm[k] = s;
        return;
    }
    __shared__ float xs[4][64];
    __shared__ float wred[4];
    int lane = tid & 63, w = tid >> 6;
    int g = blockIdx.x * 4 + w;            // wave id 0..2047
    float dsum = 0.f, nrm = 0.f;
    #pragma unroll
    for (int i = 0; i < 4; ++i) {
        int t0 = g * 16 + i * 4;
        const float* src = x + ((size_t)(t0 >> 10) << 16) + lane * 1024 + (t0 & 1023);
        float4 v = *(const float4*)src;
        #pragma unroll
        for (int s = 1; s <= 32; s <<= 1) {
            float sgn = (lane & s) ? -1.f : 1.f;
            float ox = __shfl_xor(v.x, s);
            float oy = __shfl_xor(v.y, s);
            float oz = __shfl_xor(v.z, s);
            float ow = __shfl_xor(v.w, s);
            v.x = fmaf(sgn, v.x, ox);
            v.y = fmaf(sgn, v.y, oy);
            v.z = fmaf(sgn, v.z, oz);
            v.w = fmaf(sgn, v.w, ow);
        }
        float* dst = xr + ((size_t)t0 << 6) + lane;
        dst[0]   = v.x;
        dst[64]  = v.y;
        dst[128] = v.z;
        dst[192] = v.w;
        dsum += v.x + v.y + v.z + v.w;
        nrm  += v.x*v.x + v.y*v.y + v.z*v.z + v.w*v.w;
    }
    xs[w][lane] = dsum;
    #pragma unroll
    for (int m = 32; m >= 1; m >>= 1) nrm += __shfl_xor(nrm, m);
    if (lane == 0) wred[w] = nrm;
    __syncthreads();
    if (tid < 64) atomicAdd(&xr_sum[tid], xs[0][tid] + xs[1][tid] + xs[2][tid] + xs[3][tid]);
    if (tid == 0) atomicAdd(&scal[1], wred[0] + wred[1] + wred[2] + wred[3]);
}

// ---------------------------------------------------------------------------
// 2) fused distance GEMM + argmin, inner-product form, row-major LDS (no
//    transpose, 0 bank conflicts verified in r4). Direct global->LDS staging
//    (no register prefetch: r4's pf[8] caused 24.8MB scratch spill traffic).
//    Block = 128 tokens x 512 codes (k-split 2), 8x8 per-thread tile.
#define XLD 68
__global__ __launch_bounds__(256) void k_argmin(const float* __restrict__ xr,
    const float* __restrict__ E, const float* __restrict__ enorm,
    float* __restrict__ pmin, int* __restrict__ pidx)
{
    __shared__ float xs[128 * XLD];
    __shared__ float es[128 * XLD];
    int tid = threadIdx.x;
    int tx = tid & 15, ty = tid >> 4;
    int nb = blockIdx.x >> 1, kh = blockIdx.x & 1;
    int n0 = nb << 7;

    // stage xr tile row-major (straight copy, contiguous writes)
    {
        const float4* src = (const float4*)(xr + ((size_t)n0 << 6));
        #pragma unroll
        for (int it = 0; it < 8; ++it) {
            int q = (it << 8) + tid;
            int row = q >> 4, c4 = (q & 15) << 2;
            *(float4*)(xs + row * XLD + c4) = src[q];
        }
    }

    float best[8]; int bidx[8];
    #pragma unroll
    for (int i = 0; i < 8; ++i) { best[i] = 3.4e38f; bidx[i] = 0; }

    for (int kc = 0; kc < 4; ++kc) {
        int kbase = (kh << 9) + (kc << 7);
        __syncthreads();                    // prev chunk reads done; xs staged
        {
            const float4* esrc = (const float4*)(E + ((size_t)kbase << 6));
            #pragma unroll
            for (int it = 0; it < 8; ++it) {
                int q = (it << 8) + tid;
                int row = q >> 4, c4 = (q & 15) << 2;
                *(float4*)(es + row * XLD + c4) = esrc[q];
            }
        }
        __syncthreads();

        float acc[8][8];
        #pragma unroll
        for (int i = 0; i < 8; ++i)
            #pragma unroll
            for (int j = 0; j < 8; ++j) acc[i][j] = 0.f;

        #pragma unroll 2
        for (int d4 = 0; d4 < 16; ++d4) {
            int dw = d4 << 2;
            float4 a8[8];
            #pragma unroll
            for (int i = 0; i < 8; ++i)
                a8[i] = *(const float4*)(xs + (16 * i + ty) * XLD + dw);
            #pragma unroll
            for (int j = 0; j < 8; ++j) {
                float4 b = *(const float4*)(es + (16 * j + tx) * XLD + dw);
                #pragma unroll
                for (int i = 0; i < 8; ++i) {
                    float t = fmaf(a8[i].x, b.x, acc[i][j]);
                    t = fmaf(a8[i].y, b.y, t);
                    t = fmaf(a8[i].z, b.z, t);
                    acc[i][j] = fmaf(a8[i].w, b.w, t);
                }
            }
        }

        // fold: s = ||e||^2 - 2*dot
        #pragma unroll
        for (int j = 0; j < 8; ++j) {
            int k = kbase + 16 * j + tx;
            float en = enorm[k];
            #pragma unroll
            for (int i = 0; i < 8; ++i) {
                float s = fmaf(-2.f, acc[i][j], en);
                if (s < best[i]) { best[i] = s; bidx[i] = k; }
            }
        }
    }

    // reduce across the 16 tx lanes (bits 0-3 of lane id)
    #pragma unroll
    for (int i = 0; i < 8; ++i) {
        float v = best[i]; int id = bidx[i];
        #pragma unroll
        for (int m = 8; m >= 1; m >>= 1) {
            float v2 = __shfl_xor(v, m);
            int id2 = __shfl_xor(id, m);
            if (v2 < v || (v2 == v && id2 < id)) { v = v2; id = id2; }
        }
        if (tx == 0) {
            int r = n0 + 16 * i + ty;
            pmin[(kh << 15) + r] = v;
            pidx[(kh << 15) + r] = id;
        }
    }
}

// ---------------------------------------------------------------------------
// 3) merge k-halves + counts + fused quant output & sq-error
__global__ __launch_bounds__(256) void k_mergequant(const float* __restrict__ pmin,
    const int* __restrict__ pidx, const float* __restrict__ x,
    const float* __restrict__ E, int* __restrict__ idxw,
    float* __restrict__ out_idx, float* __restrict__ counts,
    float* __restrict__ outq, float* __restrict__ scal)
{
    __shared__ int lidx[256];
    __shared__ float wr[4];
    int tid = threadIdx.x;
    int n = blockIdx.x * 256 + tid;
    float v0 = pmin[n];          int i0 = pidx[n];
    float v1 = pmin[32768 + n];  int i1 = pidx[32768 + n];
    int k = (v1 < v0 || (v1 == v0 && i1 < i0)) ? i1 : i0;
    idxw[n] = k;
    out_idx[n] = (float)k;
    atomicAdd(&counts[k], 1.0f);
    lidx[tid] = k;
    __syncthreads();

    int f40 = blockIdx.x * 4096;
    float sq = 0.f;
    #pragma unroll 4
    for (int it = 0; it < 16; ++it) {
        int q = (it << 8) + tid;
        int kk = lidx[q >> 4];
        int d4 = q & 15;
        float4 xv = ((const float4*)x)[f40 + q];
        float4 ev = ((const float4*)E)[(kk << 4) + d4];
        float dx = ev.x - xv.x, dy = ev.y - xv.y, dz = ev.z - xv.z, dw_ = ev.w - xv.w;
        ((float4*)outq)[f40 + q] = make_float4(xv.x + dx, xv.y + dy, xv.z + dz, xv.w + dw_);
        sq += dx*dx + dy*dy + dz*dz + dw_*dw_;
    }
    #pragma unroll
    for (int m = 32; m >= 1; m >>= 1) sq += __shfl_xor(sq, m);
    if ((tid & 63) == 0) wr[tid >> 6] = sq;
    __syncthreads();
    if (tid == 0) atomicAdd(&scal[0], wr[0] + wr[1] + wr[2] + wr[3]);
}

// ---------------------------------------------------------------------------
// 4) EMA cluster size + smoothing + exclusive scan (wave-shuffle version)
__global__ __launch_bounds__(1024) void k_ema_scan(const float* __restrict__ ecs,
    const float* __restrict__ counts, float* __restrict__ out_cs,
    float* __restrict__ csw, int* __restrict__ off, int* __restrict__ cur)
{
    __shared__ float wsum[16];
    __shared__ int   wcnt[16];
    __shared__ int   woff[16];
    __shared__ float nss;
    int k = threadIdx.x;
    int lane = k & 63, w = k >> 6;
    float c = counts[k];
    float cs = ecs[k] * 0.99f + 0.01f * c;
    int ci = (int)c;
    int sc = ci;
    #pragma unroll
    for (int o = 1; o < 64; o <<= 1) {
        int t = __shfl_up(sc, o);
        if (lane >= o) sc += t;
    }
    float v = cs;
    #pragma unroll
    for (int m = 32; m >= 1; m >>= 1) v += __shfl_xor(v, m);
    if (lane == 63) wcnt[w] = sc;
    if (lane == 0)  wsum[w] = v;
    __syncthreads();
    if (k < 16) {
        int t = wcnt[k];
        int e = t;
        #pragma unroll
        for (int o = 1; o < 16; o <<= 1) {
            int u = __shfl_up(e, o);
            if (k >= o) e += u;
        }
        woff[k] = e - t;
        if (k == 15) {
            float s = 0.f;
            for (int i = 0; i < 16; ++i) s += wsum[i];
            nss = s;
        }
    }
    __syncthreads();
    int offk = woff[w] + sc - ci;
    off[k] = offk;
    cur[k] = offk;
    float nn = nss;
    float csf = (cs + 1e-5f) / (nn + 1024.f * 1e-5f) * nn;
    out_cs[k] = csf;
    csw[k] = csf;
}

// ---------------------------------------------------------------------------
// 5) counting-sort scatter
__global__ __launch_bounds__(256) void k_scatter(const int* __restrict__ idxw,
    int* __restrict__ cur, int* __restrict__ sorted)
{
    int n = blockIdx.x * 256 + threadIdx.x;
    int k = idxw[n];
    int pos = atomicAdd(&cur[k], 1);
    sorted[pos] = n;
}

// ---------------------------------------------------------------------------
// 6) per-code segmented reduction -> new_ema_w, new_embedding, diversity
__global__ __launch_bounds__(256) void k_dwemb(const float* __restrict__ xr,
    const int* __restrict__ sorted, const int* __restrict__ off,
    const float* __restrict__ counts, const float* __restrict__ csw,
    const float* __restrict__ emaw, float* __restrict__ out_ew,
    float* __restrict__ out_emb, float* __restrict__ e_sum,
    float* __restrict__ scal)
{
    __shared__ float part[3][64];
    int k = blockIdx.x;
    int tid = threadIdx.x;
    int w = tid >> 6, d = tid & 63;
    int a = off[k];
    int cnt = (int)counts[k];
    int end = a + cnt;

    float sum = 0.f;
    for (int t = a + w; t < end; t += 4) {
        int tok = sorted[t];
        sum += xr[((size_t)tok << 6) + d];
    }
    if (w) part[w - 1][d] = sum;
    __syncthreads();
    if (w == 0) {
        float dw = sum + part[0][d] + part[1][d] + part[2][d];
        int i = (k << 6) + d;
        float nw = emaw[i] * 0.99f + 0.01f * dw;
        out_ew[i] = nw;
        float emb = nw / csw[k];
        out_emb[i] = emb;
        if (cnt > 0) {
            float c = (float)cnt;
            atomicAdd(&e_sum[d], c * emb);
            float t2 = c * emb * emb;
            #pragma unroll
            for (int m = 32; m >= 1; m >>= 1) t2 += __shfl_xor(t2, m);
            if (d == 0) atomicAdd(&scal[2], t2);
        }
    }
}

// ---------------------------------------------------------------------------
// 7) finalize scalars
__global__ __launch_bounds__(1024) void k_final(const float* __restrict__ counts,
    const float* __restrict__ scal, const float* __restrict__ xr_sum,
    const float* __restrict__ e_sum, float* __restrict__ out)
{
    int tid = threadIdx.x;
    float a = counts[tid] * (1.f / 32768.f);
    float t = a * logf(a + 1e-10f);
    float dc = (tid < 64) ? e_sum[tid] * xr_sum[tid] : 0.f;
    #pragma unroll
    for (int m = 32; m >= 1; m >>= 1) { t += __shfl_xor(t, m); dc += __shfl_xor(dc, m); }
    __shared__ float wt[16], wd[16];
    if ((tid & 63) == 0) { wt[tid >> 6] = t; wd[tid >> 6] = dc; }
    __syncthreads();
    if (tid == 0) {
        float S = 0.f, Dt = 0.f;
        for (int i = 0; i < 16; ++i) { S += wt[i]; Dt += wd[i]; }
        float cb = scal[0] * (1.f / 2097152.f);
        out[O_CB] = cb;
        out[O_CM] = 0.25f * cb;
        float inv = 1.f / 32768.f;
        out[O_DV] = scal[2] * inv + scal[1] * inv - 2.f * (Dt * inv * inv);
        out[O_PP] = expf(-S);
    }
}

// ---------------------------------------------------------------------------
extern "C" void kernel_launch(void* const* d_in, const int* in_sizes, int n_in,
                              void* d_out, int out_size, void* d_ws, size_t ws_size,
                              hipStream_t stream)
{
    const float* x    = (const float*)d_in[0];
    const float* E    = (const float*)d_in[1];
    const float* emaw = (const float*)d_in[3];
    const float* ecs  = (const float*)d_in[4];
    float* out = (float*)d_out;
    float* ws  = (float*)d_ws;

    hipMemsetAsync((void*)(ws + WS_COUNTS), 0,
                   (size_t)(WS_PMIN - WS_COUNTS) * sizeof(float), stream);

    hipLaunchKernelGGL(k_rotate_enorm, dim3(516), dim3(256), 0, stream,
                       x, E, ws + WS_XR, ws + WS_ENORM, ws + WS_XRSUM, ws + WS_SCAL);
    hipLaunchKernelGGL(k_argmin, dim3(512), dim3(256), 0, stream,
                       ws + WS_XR, E, ws + WS_ENORM,
                       ws + WS_PMIN, (int*)(ws + WS_PIDX));
    hipLaunchKernelGGL(k_mergequant, dim3(128), dim3(256), 0, stream,
                       ws + WS_PMIN, (const int*)(ws + WS_PIDX), x, E,
                       (int*)(ws + WS_IDX), out + O_IDX, ws + WS_COUNTS,
                       out + O_Q, ws + WS_SCAL);
    hipLaunchKernelGGL(k_ema_scan, dim3(1), dim3(1024), 0, stream,
                       ecs, ws + WS_COUNTS, out + O_CS, ws + WS_CS,
                       (int*)(ws + WS_OFF), (int*)(ws + WS_CUR));
    hipLaunchKernelGGL(k_scatter, dim3(128), dim3(256), 0, stream,
                       (const int*)(ws + WS_IDX), (int*)(ws + WS_CUR),
                       (int*)(ws + WS_SORT));
    hipLaunchKernelGGL(k_dwemb, dim3(1024), dim3(256), 0, stream,
                       ws + WS_XR, (const int*)(ws + WS_SORT),
                       (const int*)(ws + WS_OFF), ws + WS_COUNTS, ws + WS_CS,
                       emaw, out + O_EW, out + O_EMB, ws + WS_ESUM, ws + WS_SCAL);
    hipLaunchKernelGGL(k_final, dim3(1), dim3(1024), 0, stream,
                       ws + WS_COUNTS, ws + WS_SCAL, ws + WS_XRSUM,
                       ws + WS_ESUM, out);
}